// Round 6
// baseline (881.799 us; speedup 1.0000x reference)
//
#include <hip/hip_runtime.h>

#define NT 320          // threads/block (5 waves)
#define TZ 4
#define TH 4
#define PZ 6            // TZ+2
#define PH 6            // TH+2
#define STR 84          // LDS row stride in floats (21 float4 slots; odd slot stride de-phases rows)
#define PROWS (PZ*PH)   // 36 rows per channel tile
#define NSLOT (PROWS*20)// 720 float4 staging slots per channel

__device__ __forceinline__ void store_f4u(float* p, float4 v) {
    __builtin_memcpy(p, &v, 16);   // unaligned-safe 16B store
}

// Barrier with ONLY the semantically-required LDS drain (keeps VMEM in flight).
__device__ __forceinline__ void block_sync_lds() {
    asm volatile("s_waitcnt lgkmcnt(0)" ::: "memory");
    __builtin_amdgcn_s_barrier();
}

__global__ __launch_bounds__(NT)
void wincorr_kernel(const float* __restrict__ x, const float* __restrict__ y,
                    float* __restrict__ out)
{
    // Triple buffer: depth-2 software pipeline (write y(c+1) staged 2 iters ago,
    // while y(c+2), y(c+3) are in flight). 3*36*84*4B = 36.3 KB -> still 3 blocks/CU.
    __shared__ __align__(16) float buf[3][PROWS * STR];

    const long long plane = 512000;  // 80*80*80
    const int tid = threadIdx.x;
    const int twi = tid % 20;        // float4 column within row (w = 4*twi)
    const int th  = (tid / 20) % TH;
    const int tz  = tid / 80;

    const int zt = blockIdx.x, ht = blockIdx.y, b = blockIdx.z;
    const int z0 = zt * TZ, h0 = ht * TH;
    const int gz = z0 + tz, gh = h0 + th, wb = 4 * twi;

    const float* xb = x + (long long)b * 64 * plane;
    const float* yb = y + (long long)b * 64 * plane;
    const long long xoff = (long long)gz * 6400 + gh * 80 + wb;
    const long long xoffm = xoff - (wb > 0 ? 1 : 0);   // x[wb-1] (clamped; unused at edge)
    const long long xoffp = xoff + (wb < 76 ? 4 : 3);  // x[wb+4] (clamped; unused at edge)

    // ---- staging precompute: 3 float4 slots per thread (720 slots total) ----
    // Loads are UNCONDITIONAL with clamped addresses (no cndmask selects, full
    // prefetch pipelining); ds_writes are exec-masked by val[k]; permanently-
    // invalid halo slots are pre-zeroed once per buffer (val[] is channel-
    // independent, so they stay zero for the whole kernel).
    int  goff[3], loff[3];
    bool val[3];
#pragma unroll
    for (int k = 0; k < 3; ++k) {
        int s    = tid + k * NT;
        int row  = s / 20, col = s % 20;
        bool inslot = (s < NSLOT);
        int rowc = inslot ? row : (PROWS - 1);
        int pz = rowc / PH, py = rowc % PH;
        int yz = z0 - 1 + pz, yh = h0 - 1 + py;
        bool inrange = ((unsigned)yz < 80u) && ((unsigned)yh < 80u);
        val[k]  = inslot && inrange;
        int yzc = min(max(yz, 0), 79), yhc = min(max(yh, 0), 79);
        goff[k] = yzc * 6400 + yhc * 80 + 4 * col;   // always in-bounds
        loff[k] = row * STR + 4 * col;
        if (inslot && !inrange) {
            const float4 z4 = make_float4(0.f, 0.f, 0.f, 0.f);
            *(float4*)(&buf[0][loff[k]]) = z4;
            *(float4*)(&buf[1][loff[k]]) = z4;
            *(float4*)(&buf[2][loff[k]]) = z4;
        }
    }

    float4 acc[27];
#pragma unroll
    for (int o = 0; o < 27; ++o) acc[o] = make_float4(0.f, 0.f, 0.f, 0.f);

    // inner compute phase: 9 tap-rows, 1 aligned b128 each, 108 FMAs
    auto compute = [&](const float* B, float4 xv, float xml, float xpr) {
#pragma unroll
        for (int dz = 0; dz < 3; ++dz) {
#pragma unroll
            for (int dy = 0; dy < 3; ++dy) {
                const float4 r = *(const float4*)(B + ((tz + dz) * PH + (th + dy)) * STR + wb);
                const int o = (dz * 3 + dy) * 3;
                // t=0 (dx=-1): outputs [wb+1..wb+4]
                acc[o].x   += xv.y * r.x; acc[o].y   += xv.z * r.y;
                acc[o].z   += xv.w * r.z; acc[o].w   += xpr  * r.w;
                // t=1 (dx= 0): outputs [wb..wb+3]
                acc[o+1].x += xv.x * r.x; acc[o+1].y += xv.y * r.y;
                acc[o+1].z += xv.z * r.z; acc[o+1].w += xv.w * r.w;
                // t=2 (dx=+1): outputs [wb-1..wb+2]
                acc[o+2].x += xml  * r.x; acc[o+2].y += xv.x * r.y;
                acc[o+2].z += xv.y * r.z; acc[o+2].w += xv.z * r.w;
            }
        }
    };

    // ---- prologue ----
    {   // stage y(0) -> buf[0]
        float4 t0 = *(const float4*)(yb + goff[0]);
        float4 t1 = *(const float4*)(yb + goff[1]);
        float4 t2 = *(const float4*)(yb + goff[2]);
        if (val[0]) *(float4*)(&buf[0][loff[0]]) = t0;
        if (val[1]) *(float4*)(&buf[0][loff[1]]) = t1;
        if (val[2]) *(float4*)(&buf[0][loff[2]]) = t2;
    }
    // y pipeline registers: yA = y(1), yB = y(2) in flight
    float4 yA0, yA1, yA2, yB0, yB1, yB2;
    {
        const float* y1 = yb + plane;
        yA0 = *(const float4*)(y1 + goff[0]);
        yA1 = *(const float4*)(y1 + goff[1]);
        yA2 = *(const float4*)(y1 + goff[2]);
        const float* y2 = yb + 2 * plane;
        yB0 = *(const float4*)(y2 + goff[0]);
        yB1 = *(const float4*)(y2 + goff[1]);
        yB2 = *(const float4*)(y2 + goff[2]);
    }
    // x pipeline registers: xA = x(0), xB = x(1) in flight
    float4 xvA = *(const float4*)(xb + xoff);
    float  xmA = xb[xoffm], xpA = xb[xoffp];
    const float* x1 = xb + plane;
    float4 xvB = *(const float4*)(x1 + xoff);
    float  xmB = x1[xoffm], xpB = x1[xoffp];

    block_sync_lds();

    // ---- steady state: c = 0..59, branch-free VMEM (masked ds_writes only,
    //      which don't perturb the compiler's outstanding-VMEM counting) ----
#pragma unroll 3
    for (int c = 0; c < 60; ++c) {
        // 1. write y(c+1) (issued at iter c-2: ~2 iterations of vmcnt slack)
        float* W = (float*)buf[(c + 1) % 3];
        if (val[0]) *(float4*)(W + loff[0]) = yA0;
        if (val[1]) *(float4*)(W + loff[1]) = yA1;
        if (val[2]) *(float4*)(W + loff[2]) = yA2;

        // 2. issue y(c+3)
        const float* yc = yb + (long long)(c + 3) * plane;
        float4 yC0 = *(const float4*)(yc + goff[0]);
        float4 yC1 = *(const float4*)(yc + goff[1]);
        float4 yC2 = *(const float4*)(yc + goff[2]);

        // 3. issue x(c+2)
        const float* xcp = xb + (long long)(c + 2) * plane;
        float4 xvC = *(const float4*)(xcp + xoff);
        float  xmC = xcp[xoffm], xpC = xcp[xoffp];

        // 4. compute channel c (buffer written at iter c-1, one barrier ago)
        compute(buf[c % 3], xvA, xmA, xpA);
        block_sync_lds();

        // rotate pipelines
        yA0 = yB0; yA1 = yB1; yA2 = yB2;
        yB0 = yC0; yB1 = yC1; yB2 = yC2;
        xvA = xvB; xmA = xmB; xpA = xpB;
        xvB = xvC; xmB = xmC; xpB = xpC;
    }

    // ---- peeled tails (literal c => const buffer indices) ----
    {   // c = 60: full body
        float* W = (float*)buf[1];                 // (60+1)%3
        if (val[0]) *(float4*)(W + loff[0]) = yA0; // y(61)
        if (val[1]) *(float4*)(W + loff[1]) = yA1;
        if (val[2]) *(float4*)(W + loff[2]) = yA2;
        const float* yc = yb + 63LL * plane;       // issue y(63)
        float4 yC0 = *(const float4*)(yc + goff[0]);
        float4 yC1 = *(const float4*)(yc + goff[1]);
        float4 yC2 = *(const float4*)(yc + goff[2]);
        const float* xcp = xb + 62LL * plane;      // issue x(62)
        float4 xvC = *(const float4*)(xcp + xoff);
        float  xmC = xcp[xoffm], xpC = xcp[xoffp];
        compute(buf[0], xvA, xmA, xpA);            // channel 60
        block_sync_lds();
        yA0 = yB0; yA1 = yB1; yA2 = yB2;
        yB0 = yC0; yB1 = yC1; yB2 = yC2;
        xvA = xvB; xmA = xmB; xpA = xpB;
        xvB = xvC; xmB = xmC; xpB = xpC;
    }
    {   // c = 61: no y-issue
        float* W = (float*)buf[2];                 // 62%3
        if (val[0]) *(float4*)(W + loff[0]) = yA0; // y(62)
        if (val[1]) *(float4*)(W + loff[1]) = yA1;
        if (val[2]) *(float4*)(W + loff[2]) = yA2;
        const float* xcp = xb + 63LL * plane;      // issue x(63)
        float4 xvC = *(const float4*)(xcp + xoff);
        float  xmC = xcp[xoffm], xpC = xcp[xoffp];
        compute(buf[1], xvA, xmA, xpA);            // channel 61
        block_sync_lds();
        yA0 = yB0; yA1 = yB1; yA2 = yB2;           // yA = y(63)
        xvA = xvB; xmA = xmB; xpA = xpB;
        xvB = xvC; xmB = xmC; xpB = xpC;
    }
    {   // c = 62: no issues
        float* W = (float*)buf[0];                 // 63%3
        if (val[0]) *(float4*)(W + loff[0]) = yA0; // y(63)
        if (val[1]) *(float4*)(W + loff[1]) = yA1;
        if (val[2]) *(float4*)(W + loff[2]) = yA2;
        compute(buf[2], xvA, xmA, xpA);            // channel 62
        block_sync_lds();
        xvA = xvB; xmA = xmB; xpA = xpB;           // x(63)
    }
    // c = 63: compute only
    compute(buf[0], xvA, xmA, xpA);

    // epilogue: scale by 64^-0.5 = 0.125; shifted windows per dx tap
    float* ob = out + (long long)b * 27 * plane + xoff;
#pragma unroll
    for (int dz = 0; dz < 3; ++dz) {
#pragma unroll
        for (int dy = 0; dy < 3; ++dy) {
            const int o = (dz * 3 + dy) * 3;
            float4 a0 = acc[o], a1 = acc[o+1], a2 = acc[o+2];
            a0.x *= 0.125f; a0.y *= 0.125f; a0.z *= 0.125f; a0.w *= 0.125f;
            a1.x *= 0.125f; a1.y *= 0.125f; a1.z *= 0.125f; a1.w *= 0.125f;
            a2.x *= 0.125f; a2.y *= 0.125f; a2.z *= 0.125f; a2.w *= 0.125f;
            float* p0 = ob + (long long)(o    ) * plane;
            float* p1 = ob + (long long)(o + 1) * plane;
            float* p2 = ob + (long long)(o + 2) * plane;
            // t=0 (dx=-1): window [wb+1..wb+4]
            if (twi < 19) store_f4u(p0 + 1, a0);
            else { p0[1] = a0.x; p0[2] = a0.y; p0[3] = a0.z; }  // w=77,78,79; drop w=80
            if (twi == 0) p0[0] = 0.f;                          // out[w=0] = x[0]*y[-1] = 0
            // t=1 (dx=0): aligned at wb
            *(float4*)p1 = a1;
            // t=2 (dx=+1): window [wb-1..wb+2]
            if (twi > 0) store_f4u(p2 - 1, a2);
            else { p2[0] = a2.y; p2[1] = a2.z; p2[2] = a2.w; }  // w=0,1,2; drop w=-1
            if (twi == 19) p2[3] = 0.f;                         // out[w=79] = x[79]*y[80] = 0
        }
    }
}

extern "C" void kernel_launch(void* const* d_in, const int* in_sizes, int n_in,
                              void* d_out, int out_size, void* d_ws, size_t ws_size,
                              hipStream_t stream) {
    const float* x = (const float*)d_in[0];
    const float* y = (const float*)d_in[1];
    float* out = (float*)d_out;

    dim3 grid(80 / TZ, 80 / TH, 2);   // (20, 20, 2) = 800 blocks
    dim3 block(NT);
    wincorr_kernel<<<grid, block, 0, stream>>>(x, y, out);
}